// Round 1
// baseline (687.596 us; speedup 1.0000x reference)
//
#include <hip/hip_runtime.h>

#define NN 100000
#define EE 1600000
#define DIN 128
#define DOUT 64
#define NH 4

__device__ __forceinline__ float elu_f(float x) {
  return x > 0.f ? x : (__expf(x) - 1.f);
}
__device__ __forceinline__ float lrelu_f(float x) {
  return x > 0.f ? x : 0.2f * x;
}
__device__ __forceinline__ float b2f(unsigned short u) {
  union { unsigned int i; float f; } v; v.i = ((unsigned int)u) << 16; return v.f;
}
__device__ __forceinline__ unsigned short f2b(float f) {
  union { float f; unsigned int i; } v; v.f = f;
  unsigned int r = v.i + 0x7fffu + ((v.i >> 16) & 1u);
  return (unsigned short)(r >> 16);
}

// Kernel 1: CSR row_ptr from sorted edge_row via binary search (lower_bound).
__global__ __launch_bounds__(256) void build_row_ptr_k(
    const int* __restrict__ erow, int* __restrict__ rp) {
  int r = blockIdx.x * 256 + threadIdx.x;
  if (r > NN) return;
  int lo = 0, hi = EE;
  while (lo < hi) {
    int mid = (lo + hi) >> 1;
    if (erow[mid] < r) lo = mid + 1; else hi = mid;
  }
  rp[r] = lo;
}

// Kernel 2: per-head projection xh = inp @ W[h]; epilogue computes
// f1 = elu(xh @ a1), f2 = elu(xh @ a2) from fp32 accumulators, writes xh bf16
// in [N][H*64] layout for the aggregation gather.
__global__ __launch_bounds__(256) void proj_k(
    const float* __restrict__ inp, const float* __restrict__ W,
    const float* __restrict__ a1, const float* __restrict__ a2,
    float* __restrict__ f1, float* __restrict__ f2,
    unsigned short* __restrict__ xh) {
  __shared__ float lw[DIN * DOUT];  // 32 KB: W[h][k][j]
  const int h = blockIdx.y;
  const int tid = threadIdx.x;
  {
    const float4* src = (const float4*)(W + (size_t)h * DIN * DOUT);
    float4* dst = (float4*)lw;
    #pragma unroll
    for (int i = 0; i < (DIN * DOUT / 4) / 256; ++i)
      dst[tid + i * 256] = src[tid + i * 256];
  }
  __syncthreads();
  const int wave = tid >> 6, lane = tid & 63;
  int row0 = blockIdx.x * 64 + wave * 16;
  row0 = __builtin_amdgcn_readfirstlane(row0);
  if (row0 >= NN) return;
  const float a1j = a1[h * DOUT + lane];
  const float a2j = a2[h * DOUT + lane];
  float acc[16];
  #pragma unroll
  for (int r = 0; r < 16; ++r) acc[r] = 0.f;
  const int nr = (NN - row0) < 16 ? (NN - row0) : 16;
  if (nr == 16) {
    // k-outer / rows-inner: one LDS read of W feeds 16 FMAs (VALU-bound).
    for (int k4 = 0; k4 < DIN / 4; ++k4) {
      const float w0 = lw[(k4 * 4 + 0) * DOUT + lane];
      const float w1 = lw[(k4 * 4 + 1) * DOUT + lane];
      const float w2 = lw[(k4 * 4 + 2) * DOUT + lane];
      const float w3 = lw[(k4 * 4 + 3) * DOUT + lane];
      #pragma unroll
      for (int r = 0; r < 16; ++r) {
        const float4 iv = *(const float4*)(inp + (size_t)(row0 + r) * DIN + k4 * 4);
        acc[r] = fmaf(iv.x, w0, acc[r]);
        acc[r] = fmaf(iv.y, w1, acc[r]);
        acc[r] = fmaf(iv.z, w2, acc[r]);
        acc[r] = fmaf(iv.w, w3, acc[r]);
      }
    }
  } else {
    for (int r = 0; r < nr; ++r) {
      float a = 0.f;
      for (int k = 0; k < DIN; ++k)
        a = fmaf(inp[(size_t)(row0 + r) * DIN + k], lw[k * DOUT + lane], a);
      acc[r] = a;
    }
  }
  #pragma unroll
  for (int r = 0; r < 16; ++r) {
    if (r < nr) {
      const int row = row0 + r;
      const float x = acc[r];
      xh[(size_t)row * (NH * DOUT) + h * DOUT + lane] = f2b(x);
      float p1 = x * a1j, p2 = x * a2j;
      #pragma unroll
      for (int off = 32; off > 0; off >>= 1) {
        p1 += __shfl_xor(p1, off);
        p2 += __shfl_xor(p2, off);
      }
      if (lane == 0) {
        f1[(size_t)h * NN + row] = elu_f(p1);
        f2[(size_t)h * NN + row] = elu_f(p2);
      }
    }
  }
}

// Kernel 3: one wave per destination row, all 4 heads at once.
// 16-lane group g handles head g (lane's 4 output dims are within one head).
// Softmax without max-subtraction (logits bounded); single pass:
// s += exp(le); acc += exp(le) * xh[col].
__global__ __launch_bounds__(256) void agg_k(
    const int* __restrict__ rp, const int* __restrict__ ecol,
    const float* __restrict__ eval, const float* __restrict__ f1,
    const float* __restrict__ f2, const unsigned short* __restrict__ xh,
    const float* __restrict__ b, float* __restrict__ out) {
  const int tid = threadIdx.x;
  const int wave = tid >> 6, lane = tid & 63;
  const int r = blockIdx.x * 4 + wave;
  if (r >= NN) return;
  const int g = lane >> 4;  // head index for this lane group
  int e0 = rp[r], e1 = rp[r + 1];
  e0 = __builtin_amdgcn_readfirstlane(e0);
  e1 = __builtin_amdgcn_readfirstlane(e1);
  const float f1r = f1[(size_t)g * NN + r];
  float ax = 0.f, ay = 0.f, az = 0.f, aw = 0.f;
  float ssum = 0.f;
  for (int e = e0; e < e1; ++e) {
    const int c = ecol[e];       // wave-uniform
    const float v = eval[e];     // wave-uniform
    const float t = v * (f1r + f2[(size_t)g * NN + c]);  // per-group
    const float ex = __expf(lrelu_f(t));
    ssum += ex;
    const ushort4 xv = *(const ushort4*)(xh + (size_t)c * (NH * DOUT) + lane * 4);
    ax = fmaf(ex, b2f(xv.x), ax);
    ay = fmaf(ex, b2f(xv.y), ay);
    az = fmaf(ex, b2f(xv.z), az);
    aw = fmaf(ex, b2f(xv.w), aw);
  }
  const float4 bb = *(const float4*)(b + lane * 4);  // b flattened [H*64]
  const float inv = (e1 > e0) ? (1.f / ssum) : 0.f;
  float v0 = elu_f(ax * inv + bb.x);
  float v1 = elu_f(ay * inv + bb.y);
  float v2 = elu_f(az * inv + bb.z);
  float v3 = elu_f(aw * inv + bb.w);
  // mean over heads: lanes {l, l^16, l^32, l^48} hold same dim, different head
  v0 += __shfl_xor(v0, 16); v1 += __shfl_xor(v1, 16);
  v2 += __shfl_xor(v2, 16); v3 += __shfl_xor(v3, 16);
  v0 += __shfl_xor(v0, 32); v1 += __shfl_xor(v1, 32);
  v2 += __shfl_xor(v2, 32); v3 += __shfl_xor(v3, 32);
  if (lane < 16) {
    float4 o = make_float4(v0 * 0.25f, v1 * 0.25f, v2 * 0.25f, v3 * 0.25f);
    *(float4*)(out + (size_t)r * DOUT + lane * 4) = o;
  }
}

extern "C" void kernel_launch(void* const* d_in, const int* in_sizes, int n_in,
                              void* d_out, int out_size, void* d_ws, size_t ws_size,
                              hipStream_t stream) {
  const float* inp = (const float*)d_in[0];
  const float* W   = (const float*)d_in[1];
  const float* a1  = (const float*)d_in[2];
  const float* a2  = (const float*)d_in[3];
  const float* b   = (const float*)d_in[4];
  const float* ev  = (const float*)d_in[5];
  const int* erow  = (const int*)d_in[6];
  const int* ecol  = (const int*)d_in[7];
  float* out = (float*)d_out;

  char* ws = (char*)d_ws;
  size_t off = 0;
  int* rp = (int*)(ws + off);
  off += (((size_t)(NN + 1) * 4) + 255) & ~(size_t)255;
  float* f1 = (float*)(ws + off);
  off += (((size_t)NH * NN * 4) + 255) & ~(size_t)255;
  float* f2 = (float*)(ws + off);
  off += (((size_t)NH * NN * 4) + 255) & ~(size_t)255;
  unsigned short* xh = (unsigned short*)(ws + off);

  build_row_ptr_k<<<(NN + 1 + 255) / 256, 256, 0, stream>>>(erow, rp);
  dim3 pg((NN + 63) / 64, NH);
  proj_k<<<pg, 256, 0, stream>>>(inp, W, a1, a2, f1, f2, xh);
  agg_k<<<(NN + 3) / 4, 256, 0, stream>>>(rp, ecol, ev, f1, f2, xh, b, out);
}

// Round 2
// 224.696 us; speedup vs baseline: 3.0601x; 3.0601x over previous
//
#include <hip/hip_runtime.h>

#define NN 100000
#define EE 1600000
#define DIN 128
#define DOUT 64
#define NH 4

typedef __attribute__((ext_vector_type(8))) short bf16x8;
typedef __attribute__((ext_vector_type(4))) float f32x4;

__device__ __forceinline__ float elu_f(float x) {
  return x > 0.f ? x : (__expf(x) - 1.f);
}
__device__ __forceinline__ float lrelu_f(float x) {
  return x > 0.f ? x : 0.2f * x;
}
__device__ __forceinline__ float b2f(unsigned short u) {
  union { unsigned int i; float f; } v; v.i = ((unsigned int)u) << 16; return v.f;
}
__device__ __forceinline__ unsigned short f2b(float f) {
  union { float f; unsigned int i; } v; v.f = f;
  unsigned int r = v.i + 0x7fffu + ((v.i >> 16) & 1u);
  return (unsigned short)(r >> 16);
}

// Kernel 0: W [H][DIN][DOUT] fp32 -> WbfT [H*DOUT][DIN] bf16 (64 KB, L2-hot).
__global__ __launch_bounds__(256) void wbf_k(
    const float* __restrict__ W, unsigned short* __restrict__ wbt) {
  int idx = blockIdx.x * 256 + threadIdx.x;  // 32768 total
  int col = idx >> 7, k = idx & 127;         // col = h*64+j
  int h = col >> 6, j = col & 63;
  wbt[idx] = f2b(W[(size_t)h * DIN * DOUT + k * DOUT + j]);
}

// Kernel 1: CSR row_ptr from sorted edge_row via binary search.
__global__ __launch_bounds__(256) void build_row_ptr_k(
    const int* __restrict__ erow, int* __restrict__ rp) {
  int r = blockIdx.x * 256 + threadIdx.x;
  if (r > NN) return;
  int lo = 0, hi = EE;
  while (lo < hi) {
    int mid = (lo + hi) >> 1;
    if (erow[mid] < r) lo = mid + 1; else hi = mid;
  }
  rp[r] = lo;
}

// Kernel 2 (MFMA): block = 64 rows x 256 cols, 4 waves = 4 heads.
// Wave: 4 m-tiles x 4 n-tiles of 16x16, K=128 in 4 chunks of 32.
// B-frags (16) held in registers from WbfT (L2-resident); A-frags loaded
// fp32 from global (each row read once chip-wide) + cvt to bf16.
// Epilogue: xh bf16 [N][256], f1/f2 via 16-lane shuffle reduce.
__global__ __launch_bounds__(256) void proj_mfma_k(
    const float* __restrict__ inp, const unsigned short* __restrict__ wbt,
    const float* __restrict__ a1, const float* __restrict__ a2,
    float* __restrict__ f1, float* __restrict__ f2,
    unsigned short* __restrict__ xh) {
  const int tid = threadIdx.x;
  const int h = tid >> 6;   // wave = head
  const int l = tid & 63;
  const int lr = l & 15;    // A-row / B-col / D-col within tile
  const int lk = l >> 4;    // k-group (8 contiguous k each)
  const int row0 = blockIdx.x * 64;

  // B fragments: B[k][col], col = h*64 + n*16 + lr, k = kc*32 + lk*8 + j
  bf16x8 bf[4][4];
  #pragma unroll
  for (int n = 0; n < 4; ++n) {
    const int col = h * DOUT + n * 16 + lr;
    #pragma unroll
    for (int kc = 0; kc < 4; ++kc)
      bf[n][kc] = *(const bf16x8*)(wbt + (size_t)col * DIN + kc * 32 + lk * 8);
  }

  f32x4 acc[4][4];
  #pragma unroll
  for (int m = 0; m < 4; ++m)
    #pragma unroll
    for (int n = 0; n < 4; ++n)
      acc[m][n] = (f32x4)(0.f);

  #pragma unroll
  for (int m = 0; m < 4; ++m) {
    int row = row0 + m * 16 + lr;
    int rowc = row < NN ? row : NN - 1;  // clamp loads; stores guarded later
    const float* ap = inp + (size_t)rowc * DIN;
    #pragma unroll
    for (int kc = 0; kc < 4; ++kc) {
      const float4 x0 = *(const float4*)(ap + kc * 32 + lk * 8);
      const float4 x1 = *(const float4*)(ap + kc * 32 + lk * 8 + 4);
      bf16x8 av;
      av[0] = (short)f2b(x0.x); av[1] = (short)f2b(x0.y);
      av[2] = (short)f2b(x0.z); av[3] = (short)f2b(x0.w);
      av[4] = (short)f2b(x1.x); av[5] = (short)f2b(x1.y);
      av[6] = (short)f2b(x1.z); av[7] = (short)f2b(x1.w);
      #pragma unroll
      for (int n = 0; n < 4; ++n)
        acc[m][n] = __builtin_amdgcn_mfma_f32_16x16x32_bf16(
            av, bf[n][kc], acc[m][n], 0, 0, 0);
    }
  }

  // a1/a2 per-lane slices
  float a1v[4], a2v[4];
  #pragma unroll
  for (int n = 0; n < 4; ++n) {
    a1v[n] = a1[h * DOUT + n * 16 + lr];
    a2v[n] = a2[h * DOUT + n * 16 + lr];
  }

  // Epilogue. D layout: col = lr, row_local = lk*4 + reg.
  #pragma unroll
  for (int m = 0; m < 4; ++m) {
    #pragma unroll
    for (int reg = 0; reg < 4; ++reg) {
      const int row = row0 + m * 16 + lk * 4 + reg;
      const bool ok = row < NN;
      float p1 = 0.f, p2 = 0.f;
      #pragma unroll
      for (int n = 0; n < 4; ++n) {
        const float v = acc[m][n][reg];
        if (ok)
          xh[(size_t)row * (NH * DOUT) + h * DOUT + n * 16 + lr] = f2b(v);
        p1 = fmaf(v, a1v[n], p1);
        p2 = fmaf(v, a2v[n], p2);
      }
      #pragma unroll
      for (int off = 1; off < 16; off <<= 1) {
        p1 += __shfl_xor(p1, off);
        p2 += __shfl_xor(p2, off);
      }
      if (ok && lr == 0) {
        f1[(size_t)h * NN + row] = elu_f(p1);
        f2[(size_t)h * NN + row] = elu_f(p2);
      }
    }
  }
}

// Kernel 3: one wave per destination row, all 4 heads at once.
// 16-lane group g handles head g. Softmax without max-subtraction
// (logits bounded); single pass: s += exp(le); acc += exp(le) * xh[col].
__global__ __launch_bounds__(256) void agg_k(
    const int* __restrict__ rp, const int* __restrict__ ecol,
    const float* __restrict__ eval, const float* __restrict__ f1,
    const float* __restrict__ f2, const unsigned short* __restrict__ xh,
    const float* __restrict__ b, float* __restrict__ out) {
  const int tid = threadIdx.x;
  const int wave = tid >> 6, lane = tid & 63;
  const int r = blockIdx.x * 4 + wave;
  if (r >= NN) return;
  const int g = lane >> 4;  // head index for this lane group
  int e0 = rp[r], e1 = rp[r + 1];
  e0 = __builtin_amdgcn_readfirstlane(e0);
  e1 = __builtin_amdgcn_readfirstlane(e1);
  const float f1r = f1[(size_t)g * NN + r];
  float ax = 0.f, ay = 0.f, az = 0.f, aw = 0.f;
  float ssum = 0.f;
  for (int e = e0; e < e1; ++e) {
    const int c = ecol[e];       // wave-uniform
    const float v = eval[e];     // wave-uniform
    const float t = v * (f1r + f2[(size_t)g * NN + c]);  // per-group
    const float ex = __expf(lrelu_f(t));
    ssum += ex;
    const ushort4 xv = *(const ushort4*)(xh + (size_t)c * (NH * DOUT) + lane * 4);
    ax = fmaf(ex, b2f(xv.x), ax);
    ay = fmaf(ex, b2f(xv.y), ay);
    az = fmaf(ex, b2f(xv.z), az);
    aw = fmaf(ex, b2f(xv.w), aw);
  }
  const float4 bb = *(const float4*)(b + lane * 4);  // b flattened [H*64]
  const float inv = (e1 > e0) ? (1.f / ssum) : 0.f;
  float v0 = elu_f(ax * inv + bb.x);
  float v1 = elu_f(ay * inv + bb.y);
  float v2 = elu_f(az * inv + bb.z);
  float v3 = elu_f(aw * inv + bb.w);
  // mean over heads: lanes {l, l^16, l^32, l^48} hold same dim, different head
  v0 += __shfl_xor(v0, 16); v1 += __shfl_xor(v1, 16);
  v2 += __shfl_xor(v2, 16); v3 += __shfl_xor(v3, 16);
  v0 += __shfl_xor(v0, 32); v1 += __shfl_xor(v1, 32);
  v2 += __shfl_xor(v2, 32); v3 += __shfl_xor(v3, 32);
  if (lane < 16) {
    float4 o = make_float4(v0 * 0.25f, v1 * 0.25f, v2 * 0.25f, v3 * 0.25f);
    *(float4*)(out + (size_t)r * DOUT + lane * 4) = o;
  }
}

extern "C" void kernel_launch(void* const* d_in, const int* in_sizes, int n_in,
                              void* d_out, int out_size, void* d_ws, size_t ws_size,
                              hipStream_t stream) {
  const float* inp = (const float*)d_in[0];
  const float* W   = (const float*)d_in[1];
  const float* a1  = (const float*)d_in[2];
  const float* a2  = (const float*)d_in[3];
  const float* b   = (const float*)d_in[4];
  const float* ev  = (const float*)d_in[5];
  const int* erow  = (const int*)d_in[6];
  const int* ecol  = (const int*)d_in[7];
  float* out = (float*)d_out;

  char* ws = (char*)d_ws;
  size_t off = 0;
  int* rp = (int*)(ws + off);
  off += (((size_t)(NN + 1) * 4) + 255) & ~(size_t)255;
  float* f1 = (float*)(ws + off);
  off += (((size_t)NH * NN * 4) + 255) & ~(size_t)255;
  float* f2 = (float*)(ws + off);
  off += (((size_t)NH * NN * 4) + 255) & ~(size_t)255;
  unsigned short* xh = (unsigned short*)(ws + off);
  off += (((size_t)NN * NH * DOUT * 2) + 255) & ~(size_t)255;
  unsigned short* wbt = (unsigned short*)(ws + off);

  wbf_k<<<(NH * DIN * DOUT) / 256, 256, 0, stream>>>(W, wbt);
  build_row_ptr_k<<<(NN + 1 + 255) / 256, 256, 0, stream>>>(erow, rp);
  proj_mfma_k<<<(NN + 63) / 64, 256, 0, stream>>>(inp, wbt, a1, a2, f1, f2, xh);
  agg_k<<<(NN + 3) / 4, 256, 0, stream>>>(rp, ecol, ev, f1, f2, xh, b, out);
}

// Round 3
// 202.885 us; speedup vs baseline: 3.3891x; 1.1075x over previous
//
#include <hip/hip_runtime.h>

#define NN 100000
#define EE 1600000
#define DIN 128
#define DOUT 64
#define NH 4

typedef __attribute__((ext_vector_type(8))) short bf16x8;
typedef __attribute__((ext_vector_type(4))) float f32x4;

__device__ __forceinline__ float elu_f(float x) {
  return x > 0.f ? x : (__expf(x) - 1.f);
}
__device__ __forceinline__ float lrelu_f(float x) {
  return x > 0.f ? x : 0.2f * x;
}
__device__ __forceinline__ float b2f(unsigned short u) {
  union { unsigned int i; float f; } v; v.i = ((unsigned int)u) << 16; return v.f;
}
__device__ __forceinline__ unsigned short f2b(float f) {
  union { float f; unsigned int i; } v; v.f = f;
  unsigned int r = v.i + 0x7fffu + ((v.i >> 16) & 1u);
  return (unsigned short)(r >> 16);
}

// Kernel 0: W [H][DIN][DOUT] fp32 -> WbfT [H*DOUT][DIN] bf16 (64 KB, L2-hot).
__global__ __launch_bounds__(256) void wbf_k(
    const float* __restrict__ W, unsigned short* __restrict__ wbt) {
  int idx = blockIdx.x * 256 + threadIdx.x;  // 32768 total
  int col = idx >> 7, k = idx & 127;         // col = h*64+j
  int h = col >> 6, j = col & 63;
  wbt[idx] = f2b(W[(size_t)h * DIN * DOUT + k * DOUT + j]);
}

// Kernel 1: CSR row_ptr from sorted edge_row via binary search.
__global__ __launch_bounds__(256) void build_row_ptr_k(
    const int* __restrict__ erow, int* __restrict__ rp) {
  int r = blockIdx.x * 256 + threadIdx.x;
  if (r > NN) return;
  int lo = 0, hi = EE;
  while (lo < hi) {
    int mid = (lo + hi) >> 1;
    if (erow[mid] < r) lo = mid + 1; else hi = mid;
  }
  rp[r] = lo;
}

// Kernel 2 (MFMA): block = 64 rows x 256 cols, 4 waves = 4 heads.
// f1/f2 written PACKED as [N][4] (head-minor) so agg touches one line/edge.
__global__ __launch_bounds__(256) void proj_mfma_k(
    const float* __restrict__ inp, const unsigned short* __restrict__ wbt,
    const float* __restrict__ a1, const float* __restrict__ a2,
    float* __restrict__ f1p, float* __restrict__ f2p,
    unsigned short* __restrict__ xh) {
  const int tid = threadIdx.x;
  const int h = tid >> 6;   // wave = head
  const int l = tid & 63;
  const int lr = l & 15;    // A-row / B-col / D-col within tile
  const int lk = l >> 4;    // k-group (8 contiguous k each)
  const int row0 = blockIdx.x * 64;

  // B fragments: B[k][col], col = h*64 + n*16 + lr, k = kc*32 + lk*8 + j
  bf16x8 bf[4][4];
  #pragma unroll
  for (int n = 0; n < 4; ++n) {
    const int col = h * DOUT + n * 16 + lr;
    #pragma unroll
    for (int kc = 0; kc < 4; ++kc)
      bf[n][kc] = *(const bf16x8*)(wbt + (size_t)col * DIN + kc * 32 + lk * 8);
  }

  f32x4 acc[4][4];
  #pragma unroll
  for (int m = 0; m < 4; ++m)
    #pragma unroll
    for (int n = 0; n < 4; ++n)
      acc[m][n] = (f32x4)(0.f);

  #pragma unroll
  for (int m = 0; m < 4; ++m) {
    int row = row0 + m * 16 + lr;
    int rowc = row < NN ? row : NN - 1;  // clamp loads; stores guarded later
    const float* ap = inp + (size_t)rowc * DIN;
    #pragma unroll
    for (int kc = 0; kc < 4; ++kc) {
      const float4 x0 = *(const float4*)(ap + kc * 32 + lk * 8);
      const float4 x1 = *(const float4*)(ap + kc * 32 + lk * 8 + 4);
      bf16x8 av;
      av[0] = (short)f2b(x0.x); av[1] = (short)f2b(x0.y);
      av[2] = (short)f2b(x0.z); av[3] = (short)f2b(x0.w);
      av[4] = (short)f2b(x1.x); av[5] = (short)f2b(x1.y);
      av[6] = (short)f2b(x1.z); av[7] = (short)f2b(x1.w);
      #pragma unroll
      for (int n = 0; n < 4; ++n)
        acc[m][n] = __builtin_amdgcn_mfma_f32_16x16x32_bf16(
            av, bf[n][kc], acc[m][n], 0, 0, 0);
    }
  }

  float a1v[4], a2v[4];
  #pragma unroll
  for (int n = 0; n < 4; ++n) {
    a1v[n] = a1[h * DOUT + n * 16 + lr];
    a2v[n] = a2[h * DOUT + n * 16 + lr];
  }

  // Epilogue. D layout: col = lr, row_local = lk*4 + reg.
  #pragma unroll
  for (int m = 0; m < 4; ++m) {
    #pragma unroll
    for (int reg = 0; reg < 4; ++reg) {
      const int row = row0 + m * 16 + lk * 4 + reg;
      const bool ok = row < NN;
      float p1 = 0.f, p2 = 0.f;
      #pragma unroll
      for (int n = 0; n < 4; ++n) {
        const float v = acc[m][n][reg];
        if (ok)
          xh[(size_t)row * (NH * DOUT) + h * DOUT + n * 16 + lr] = f2b(v);
        p1 = fmaf(v, a1v[n], p1);
        p2 = fmaf(v, a2v[n], p2);
      }
      #pragma unroll
      for (int off = 1; off < 16; off <<= 1) {
        p1 += __shfl_xor(p1, off);
        p2 += __shfl_xor(p2, off);
      }
      if (ok && lr == 0) {
        f1p[(size_t)row * NH + h] = elu_f(p1);
        f2p[(size_t)row * NH + h] = elu_f(p2);
      }
    }
  }
}

// Kernel 3: one wave per destination row, all 4 heads at once.
// 16-lane group g = head g. Edge loop pipelined 4-deep: 4 independent
// xh gathers + 4 f2 gathers in flight per wave (latency hiding).
__global__ __launch_bounds__(256) void agg_k(
    const int* __restrict__ rp, const int* __restrict__ ecol,
    const float* __restrict__ eval, const float* __restrict__ f1p,
    const float* __restrict__ f2p, const unsigned short* __restrict__ xh,
    const float* __restrict__ b, float* __restrict__ out) {
  const int tid = threadIdx.x;
  const int wave = tid >> 6, lane = tid & 63;
  const int r = blockIdx.x * 4 + wave;
  if (r >= NN) return;
  const int g = lane >> 4;  // head index for this lane group
  int e0 = rp[r], e1 = rp[r + 1];
  e0 = __builtin_amdgcn_readfirstlane(e0);
  e1 = __builtin_amdgcn_readfirstlane(e1);
  const float f1r = f1p[(size_t)r * NH + g];
  float ax = 0.f, ay = 0.f, az = 0.f, aw = 0.f;
  float ssum = 0.f;
  int e = e0;
  for (; e + 4 <= e1; e += 4) {
    int c[4]; float vv[4];
    #pragma unroll
    for (int u = 0; u < 4; ++u) { c[u] = ecol[e + u]; vv[u] = eval[e + u]; }
    ushort4 xv[4]; float f2v[4];
    #pragma unroll
    for (int u = 0; u < 4; ++u) {
      xv[u] = *(const ushort4*)(xh + (size_t)c[u] * (NH * DOUT) + lane * 4);
      f2v[u] = f2p[(size_t)c[u] * NH + g];
    }
    #pragma unroll
    for (int u = 0; u < 4; ++u) {
      const float ex = __expf(lrelu_f(vv[u] * (f1r + f2v[u])));
      ssum += ex;
      ax = fmaf(ex, b2f(xv[u].x), ax);
      ay = fmaf(ex, b2f(xv[u].y), ay);
      az = fmaf(ex, b2f(xv[u].z), az);
      aw = fmaf(ex, b2f(xv[u].w), aw);
    }
  }
  for (; e < e1; ++e) {
    const int c = ecol[e];
    const float t = eval[e] * (f1r + f2p[(size_t)c * NH + g]);
    const float ex = __expf(lrelu_f(t));
    ssum += ex;
    const ushort4 xv = *(const ushort4*)(xh + (size_t)c * (NH * DOUT) + lane * 4);
    ax = fmaf(ex, b2f(xv.x), ax);
    ay = fmaf(ex, b2f(xv.y), ay);
    az = fmaf(ex, b2f(xv.z), az);
    aw = fmaf(ex, b2f(xv.w), aw);
  }
  const float4 bb = *(const float4*)(b + lane * 4);  // b flattened [H*64]
  const float inv = (e1 > e0) ? (1.f / ssum) : 0.f;
  float v0 = elu_f(ax * inv + bb.x);
  float v1 = elu_f(ay * inv + bb.y);
  float v2 = elu_f(az * inv + bb.z);
  float v3 = elu_f(aw * inv + bb.w);
  // mean over heads: lanes {l, l^16, l^32, l^48} hold same dim, different head
  v0 += __shfl_xor(v0, 16); v1 += __shfl_xor(v1, 16);
  v2 += __shfl_xor(v2, 16); v3 += __shfl_xor(v3, 16);
  v0 += __shfl_xor(v0, 32); v1 += __shfl_xor(v1, 32);
  v2 += __shfl_xor(v2, 32); v3 += __shfl_xor(v3, 32);
  if (lane < 16) {
    float4 o = make_float4(v0 * 0.25f, v1 * 0.25f, v2 * 0.25f, v3 * 0.25f);
    *(float4*)(out + (size_t)r * DOUT + lane * 4) = o;
  }
}

extern "C" void kernel_launch(void* const* d_in, const int* in_sizes, int n_in,
                              void* d_out, int out_size, void* d_ws, size_t ws_size,
                              hipStream_t stream) {
  const float* inp = (const float*)d_in[0];
  const float* W   = (const float*)d_in[1];
  const float* a1  = (const float*)d_in[2];
  const float* a2  = (const float*)d_in[3];
  const float* b   = (const float*)d_in[4];
  const float* ev  = (const float*)d_in[5];
  const int* erow  = (const int*)d_in[6];
  const int* ecol  = (const int*)d_in[7];
  float* out = (float*)d_out;

  char* ws = (char*)d_ws;
  size_t off = 0;
  int* rp = (int*)(ws + off);
  off += (((size_t)(NN + 1) * 4) + 255) & ~(size_t)255;
  float* f1p = (float*)(ws + off);
  off += (((size_t)NH * NN * 4) + 255) & ~(size_t)255;
  float* f2p = (float*)(ws + off);
  off += (((size_t)NH * NN * 4) + 255) & ~(size_t)255;
  unsigned short* xh = (unsigned short*)(ws + off);
  off += (((size_t)NN * NH * DOUT * 2) + 255) & ~(size_t)255;
  unsigned short* wbt = (unsigned short*)(ws + off);

  wbf_k<<<(NH * DIN * DOUT) / 256, 256, 0, stream>>>(W, wbt);
  build_row_ptr_k<<<(NN + 1 + 255) / 256, 256, 0, stream>>>(erow, rp);
  proj_mfma_k<<<(NN + 63) / 64, 256, 0, stream>>>(inp, wbt, a1, a2, f1p, f2p, xh);
  agg_k<<<(NN + 3) / 4, 256, 0, stream>>>(rp, ecol, ev, f1p, f2p, xh, b, out);
}

// Round 5
// 177.207 us; speedup vs baseline: 3.8802x; 1.1449x over previous
//
#include <hip/hip_runtime.h>

#define NN 100000
#define EE 1600000
#define DIN 128
#define DOUT 64
#define NH 4

typedef __attribute__((ext_vector_type(8))) short bf16x8;
typedef __attribute__((ext_vector_type(4))) float f32x4;

__device__ __forceinline__ float elu_f(float x) {
  return x > 0.f ? x : (__expf(x) - 1.f);
}
__device__ __forceinline__ float lrelu_f(float x) {
  return x > 0.f ? x : 0.2f * x;
}
__device__ __forceinline__ float b2f(unsigned short u) {
  union { unsigned int i; float f; } v; v.i = ((unsigned int)u) << 16; return v.f;
}
__device__ __forceinline__ unsigned short f2b(float f) {
  union { float f; unsigned int i; } v; v.f = f;
  unsigned int r = v.i + 0x7fffu + ((v.i >> 16) & 1u);
  return (unsigned short)(r >> 16);
}

// Kernel 0: W [H][DIN][DOUT] fp32 -> WbfT [H*DOUT][DIN] bf16 (64 KB, L2-hot).
__global__ __launch_bounds__(256) void wbf_k(
    const float* __restrict__ W, unsigned short* __restrict__ wbt) {
  int idx = blockIdx.x * 256 + threadIdx.x;  // 32768 total
  int col = idx >> 7, k = idx & 127;         // col = h*64+j
  int h = col >> 6, j = col & 63;
  wbt[idx] = f2b(W[(size_t)h * DIN * DOUT + k * DOUT + j]);
}

// Kernel 1: CSR row_ptr from sorted edge_row via binary search.
__global__ __launch_bounds__(256) void build_row_ptr_k(
    const int* __restrict__ erow, int* __restrict__ rp) {
  int r = blockIdx.x * 256 + threadIdx.x;
  if (r > NN) return;
  int lo = 0, hi = EE;
  while (lo < hi) {
    int mid = (lo + hi) >> 1;
    if (erow[mid] < r) lo = mid + 1; else hi = mid;
  }
  rp[r] = lo;
}

// Kernel 2 (MFMA): block = 64 rows x 256 cols, 4 waves = 4 heads.
// A staged once into LDS as bf16 (XOR-swizzled), shared by the 4 waves.
// MFMA operands SWAPPED (W as 'a', input as 'b') -> D = xh^T fragment:
// lane holds 4 contiguous xh cols per tile -> coalesced ushort4 stores,
// and f1/f2 reduce is 2 shfls (across the lk groups).
__global__ __launch_bounds__(256) void proj_mfma_k(
    const float* __restrict__ inp, const unsigned short* __restrict__ wbt,
    const float* __restrict__ a1, const float* __restrict__ a2,
    float* __restrict__ f1p, float* __restrict__ f2p,
    unsigned short* __restrict__ xh) {
  __shared__ unsigned short lds_a[64 * 128];  // 16 KB bf16 A-tile, swizzled
  const int tid = threadIdx.x;
  const int h = tid >> 6;   // wave = head
  const int l = tid & 63;
  const int lr = l & 15;
  const int lk = l >> 4;
  const int row0 = blockIdx.x * 64;

  // --- stage A: 64 rows x 128 k, fp32 -> bf16, swizzle byte^=(row&7)<<4 ---
  #pragma unroll
  for (int i = 0; i < 8; ++i) {
    const int idx = i * 256 + tid;       // float4 index, 2048 total
    const int row = idx >> 5;            // 0..63
    const int c4 = idx & 31;             // float4 chunk within row
    int grow = row0 + row;
    if (grow >= NN) grow = NN - 1;
    const float4 v = *(const float4*)(inp + (size_t)grow * DIN + c4 * 4);
    ushort4 w;
    w.x = f2b(v.x); w.y = f2b(v.y); w.z = f2b(v.z); w.w = f2b(v.w);
    const int byte_off = row * 256 + ((c4 * 8) ^ ((row & 7) << 4));
    *(ushort4*)((char*)lds_a + byte_off) = w;
  }

  // W fragments while staging is in flight: 'a' operand, col = h*64+n*16+lr
  bf16x8 bf[4][4];
  #pragma unroll
  for (int n = 0; n < 4; ++n) {
    const int col = h * DOUT + n * 16 + lr;
    #pragma unroll
    for (int kc = 0; kc < 4; ++kc)
      bf[n][kc] = *(const bf16x8*)(wbt + (size_t)col * DIN + kc * 32 + lk * 8);
  }
  __syncthreads();

  f32x4 acc[4][4];
  #pragma unroll
  for (int m = 0; m < 4; ++m)
    #pragma unroll
    for (int n = 0; n < 4; ++n)
      acc[m][n] = (f32x4)(0.f);

  #pragma unroll
  for (int m = 0; m < 4; ++m) {
    const int r = m * 16 + lr;
    bf16x8 af[4];
    #pragma unroll
    for (int kc = 0; kc < 4; ++kc)
      af[kc] = *(const bf16x8*)((char*)lds_a + r * 256 +
                                ((kc * 64 + lk * 16) ^ ((r & 7) << 4)));
    #pragma unroll
    for (int kc = 0; kc < 4; ++kc)
      #pragma unroll
      for (int n = 0; n < 4; ++n)
        acc[m][n] = __builtin_amdgcn_mfma_f32_16x16x32_bf16(
            bf[n][kc], af[kc], acc[m][n], 0, 0, 0);
  }

  // epilogue: lane holds xh[row0+m*16+lr][h*64 + n*16 + lk*4 + reg]
  float4 a1q[4], a2q[4];
  #pragma unroll
  for (int n = 0; n < 4; ++n) {
    a1q[n] = *(const float4*)(a1 + h * DOUT + n * 16 + lk * 4);
    a2q[n] = *(const float4*)(a2 + h * DOUT + n * 16 + lk * 4);
  }
  #pragma unroll
  for (int m = 0; m < 4; ++m) {
    const int row = row0 + m * 16 + lr;
    const bool ok = row < NN;
    float p1 = 0.f, p2 = 0.f;
    #pragma unroll
    for (int n = 0; n < 4; ++n) {
      const f32x4 a = acc[m][n];
      ushort4 pk;
      pk.x = f2b(a[0]); pk.y = f2b(a[1]); pk.z = f2b(a[2]); pk.w = f2b(a[3]);
      if (ok)
        *(ushort4*)(xh + (size_t)row * (NH * DOUT) + h * DOUT + n * 16 + lk * 4) = pk;
      p1 = fmaf(a[0], a1q[n].x, p1); p1 = fmaf(a[1], a1q[n].y, p1);
      p1 = fmaf(a[2], a1q[n].z, p1); p1 = fmaf(a[3], a1q[n].w, p1);
      p2 = fmaf(a[0], a2q[n].x, p2); p2 = fmaf(a[1], a2q[n].y, p2);
      p2 = fmaf(a[2], a2q[n].z, p2); p2 = fmaf(a[3], a2q[n].w, p2);
    }
    p1 += __shfl_xor(p1, 16); p1 += __shfl_xor(p1, 32);
    p2 += __shfl_xor(p2, 16); p2 += __shfl_xor(p2, 32);
    if (ok && lk == 0) {
      f1p[(size_t)row * NH + h] = elu_f(p1);
      f2p[(size_t)row * NH + h] = elu_f(p2);
    }
  }
}

// Kernel 3: one wave per destination row, all 4 heads at once.
// 16-lane group g = head g. 8-deep pipelined edge loop; tail handled by a
// masked 8-batch (clamped indices) so short rows keep full MLP.
__global__ __launch_bounds__(256) void agg_k(
    const int* __restrict__ rp, const int* __restrict__ ecol,
    const float* __restrict__ eval, const float* __restrict__ f1p,
    const float* __restrict__ f2p, const unsigned short* __restrict__ xh,
    const float* __restrict__ b, float* __restrict__ out) {
  const int tid = threadIdx.x;
  const int wave = tid >> 6, lane = tid & 63;
  const int r = blockIdx.x * 4 + wave;
  if (r >= NN) return;
  const int g = lane >> 4;  // head index for this lane group
  int e0 = __builtin_amdgcn_readfirstlane(rp[r]);
  int e1 = __builtin_amdgcn_readfirstlane(rp[r + 1]);
  const float f1r = f1p[(size_t)r * NH + g];
  float ax = 0.f, ay = 0.f, az = 0.f, aw = 0.f;
  float ssum = 0.f;
  int e = e0;
  for (; e + 8 <= e1; e += 8) {
    int c[8]; float vv[8];
    #pragma unroll
    for (int u = 0; u < 8; ++u) { c[u] = ecol[e + u]; vv[u] = eval[e + u]; }
    ushort4 xv[8]; float f2v[8];
    #pragma unroll
    for (int u = 0; u < 8; ++u) {
      xv[u] = *(const ushort4*)(xh + (size_t)c[u] * (NH * DOUT) + lane * 4);
      f2v[u] = f2p[(size_t)c[u] * NH + g];
    }
    #pragma unroll
    for (int u = 0; u < 8; ++u) {
      const float ex = __expf(lrelu_f(vv[u] * (f1r + f2v[u])));
      ssum += ex;
      ax = fmaf(ex, b2f(xv[u].x), ax);
      ay = fmaf(ex, b2f(xv[u].y), ay);
      az = fmaf(ex, b2f(xv[u].z), az);
      aw = fmaf(ex, b2f(xv[u].w), aw);
    }
  }
  if (e < e1) {
    int c[8]; float vv[8]; bool okk[8];
    #pragma unroll
    for (int u = 0; u < 8; ++u) {
      int ee = e + u;
      okk[u] = ee < e1;
      if (!okk[u]) ee = e1 - 1;
      c[u] = ecol[ee]; vv[u] = eval[ee];
    }
    ushort4 xv[8]; float f2v[8];
    #pragma unroll
    for (int u = 0; u < 8; ++u) {
      xv[u] = *(const ushort4*)(xh + (size_t)c[u] * (NH * DOUT) + lane * 4);
      f2v[u] = f2p[(size_t)c[u] * NH + g];
    }
    #pragma unroll
    for (int u = 0; u < 8; ++u) {
      float ex = __expf(lrelu_f(vv[u] * (f1r + f2v[u])));
      ex = okk[u] ? ex : 0.f;
      ssum += ex;
      ax = fmaf(ex, b2f(xv[u].x), ax);
      ay = fmaf(ex, b2f(xv[u].y), ay);
      az = fmaf(ex, b2f(xv[u].z), az);
      aw = fmaf(ex, b2f(xv[u].w), aw);
    }
  }
  const float4 bb = *(const float4*)(b + lane * 4);  // b flattened [H*64]
  const float inv = (e1 > e0) ? (1.f / ssum) : 0.f;
  float v0 = elu_f(ax * inv + bb.x);
  float v1 = elu_f(ay * inv + bb.y);
  float v2 = elu_f(az * inv + bb.z);
  float v3 = elu_f(aw * inv + bb.w);
  // mean over heads: lanes {l, l^16, l^32, l^48} hold same dim, different head
  v0 += __shfl_xor(v0, 16); v1 += __shfl_xor(v1, 16);
  v2 += __shfl_xor(v2, 16); v3 += __shfl_xor(v3, 16);
  v0 += __shfl_xor(v0, 32); v1 += __shfl_xor(v1, 32);
  v2 += __shfl_xor(v2, 32); v3 += __shfl_xor(v3, 32);
  if (lane < 16) {
    f32x4 o = {v0 * 0.25f, v1 * 0.25f, v2 * 0.25f, v3 * 0.25f};
    __builtin_nontemporal_store(o, (f32x4*)(out + (size_t)r * DOUT + lane * 4));
  }
}

extern "C" void kernel_launch(void* const* d_in, const int* in_sizes, int n_in,
                              void* d_out, int out_size, void* d_ws, size_t ws_size,
                              hipStream_t stream) {
  const float* inp = (const float*)d_in[0];
  const float* W   = (const float*)d_in[1];
  const float* a1  = (const float*)d_in[2];
  const float* a2  = (const float*)d_in[3];
  const float* b   = (const float*)d_in[4];
  const float* ev  = (const float*)d_in[5];
  const int* erow  = (const int*)d_in[6];
  const int* ecol  = (const int*)d_in[7];
  float* out = (float*)d_out;

  char* ws = (char*)d_ws;
  size_t off = 0;
  int* rp = (int*)(ws + off);
  off += (((size_t)(NN + 1) * 4) + 255) & ~(size_t)255;
  float* f1p = (float*)(ws + off);
  off += (((size_t)NH * NN * 4) + 255) & ~(size_t)255;
  float* f2p = (float*)(ws + off);
  off += (((size_t)NH * NN * 4) + 255) & ~(size_t)255;
  unsigned short* xh = (unsigned short*)(ws + off);
  off += (((size_t)NN * NH * DOUT * 2) + 255) & ~(size_t)255;
  unsigned short* wbt = (unsigned short*)(ws + off);

  wbf_k<<<(NH * DIN * DOUT) / 256, 256, 0, stream>>>(W, wbt);
  build_row_ptr_k<<<(NN + 1 + 255) / 256, 256, 0, stream>>>(erow, rp);
  proj_mfma_k<<<(NN + 63) / 64, 256, 0, stream>>>(inp, wbt, a1, a2, f1p, f2p, xh);
  agg_k<<<(NN + 3) / 4, 256, 0, stream>>>(rp, ecol, ev, f1p, f2p, xh, b, out);
}